// Round 2
// baseline (632.505 us; speedup 1.0000x reference)
//
#include <hip/hip_runtime.h>
#include <math.h>

#define Bb 64
#define Dd 4096
#define Hh 32
#define Kk 128
#define Vv 128
#define Mm 4096
#define MC 4097

// workspace layout (float offsets)
#define WS_Q      0
#define WS_NEWK   (WS_Q + Bb*Hh*Kk)        // 262144
#define WS_NEWV   (WS_NEWK + Bb*Kk)        // 270336
#define WS_LOGITS (WS_NEWV + Bb*Vv)        // 278528
#define WS_SMAX   (WS_LOGITS + Bb*Hh*MC)   // 8669184
#define WS_SSUM   (WS_SMAX + Bb*Hh)        // 8671232
#define WS_O      (WS_SSUM + Bb*Hh)        // 8673280

// d_out layout (float offsets): y, Kc, Vc
#define OUT_Y  0
#define OUT_KC (Bb*Dd)                      // 262144
#define OUT_VC (OUT_KC + Bb*MC*Kk)          // 33824768

// ---------------- K1: q = x @ P_q (per head), new_k = x @ P_k, new_v = x @ P_v
// grid (34, 32): x = head index (32,33 => P_k,P_v), y = d-chunk of 128
__global__ __launch_bounds__(256) void k1_proj(const float* __restrict__ x,
        const float* __restrict__ Pq, const float* __restrict__ Pk,
        const float* __restrict__ Pv, float* __restrict__ ws) {
    const int hidx = blockIdx.x;
    const int d0c  = blockIdx.y * 128;
    const int t = threadIdx.x;
    const int kg = t & 15, bg = t >> 4;
    const int k0 = kg * 8, b0 = bg * 4;

    const bool isq = (hidx < Hh);
    const float* P;
    float* out;
    if (isq)            { P = Pq + (size_t)hidx * Dd * Kk; out = ws + WS_Q; }
    else if (hidx == Hh){ P = Pk;                          out = ws + WS_NEWK; }
    else                { P = Pv;                          out = ws + WS_NEWV; }

    __shared__ float xs[32 * 65];      // [d-sub][b], stride 65 -> conflict-free
    __shared__ float ps[32 * 128];     // [d-sub][k], natural

    float acc[4][8];
    #pragma unroll
    for (int a = 0; a < 4; a++)
        #pragma unroll
        for (int c = 0; c < 8; c++) acc[a][c] = 0.f;

    for (int tt = 0; tt < 4; tt++) {
        const int d0 = d0c + tt * 32;
        #pragma unroll
        for (int ii = 0; ii < 8; ii++) {   // xs: 2048 scalars, coalesced read
            int f = ii * 256 + t;
            int i = f & 31, bb = f >> 5;
            xs[i * 65 + bb] = x[(size_t)bb * Dd + d0 + i];
        }
        #pragma unroll
        for (int ii = 0; ii < 4; ii++) {   // ps: 1024 float4
            int f = ii * 256 + t;
            int i = f >> 5, k4 = (f & 31) * 4;
            *(float4*)&ps[i * 128 + k4] = *(const float4*)&P[(size_t)(d0 + i) * Kk + k4];
        }
        __syncthreads();
        #pragma unroll
        for (int i = 0; i < 32; i++) {
            float xb[4];
            #pragma unroll
            for (int a = 0; a < 4; a++) xb[a] = xs[i * 65 + b0 + a];
            float4 p0 = *(float4*)&ps[i * 128 + k0];
            float4 p1 = *(float4*)&ps[i * 128 + k0 + 4];
            float pp[8] = {p0.x, p0.y, p0.z, p0.w, p1.x, p1.y, p1.z, p1.w};
            #pragma unroll
            for (int a = 0; a < 4; a++)
                #pragma unroll
                for (int c = 0; c < 8; c++)
                    acc[a][c] = fmaf(xb[a], pp[c], acc[a][c]);
        }
        __syncthreads();
    }
    #pragma unroll
    for (int a = 0; a < 4; a++) {
        int b = b0 + a;
        #pragma unroll
        for (int c = 0; c < 8; c++) {
            int k = k0 + c;
            size_t idx = isq ? ((size_t)(b * Hh + hidx) * Kk + k)
                             : ((size_t)b * Kk + k);
            atomicAdd(&out[idx], acc[a][c]);
        }
    }
}

// ---------------- K2: copy prev_K -> Kc, fused logits[b,h,m] = q[b,h,:].Kc[b,m,:]
// grid (64 m-tiles, 64 b), block 128. K kept NATURAL [m][k] (stride 129).
__global__ __launch_bounds__(128) void k2_kcopy_logits(const float* __restrict__ prevK,
        const float* __restrict__ wq, float* __restrict__ outKc,
        float* __restrict__ logits) {
    const int m0 = blockIdx.x * 64;
    const int b  = blockIdx.y;
    const int t  = threadIdx.x;
    __shared__ float qs[128 * 36];   // [k][h], padded, 16B-aligned rows
    __shared__ float ks[64 * 129];   // [m][k], stride 129 -> conflict-free

    #pragma unroll
    for (int ii = 0; ii < 32; ii++) {     // qs transpose-stage, h-fast (free writes)
        int f = ii * 128 + t;
        int h = f & 31, k = f >> 5;
        qs[k * 36 + h] = wq[((size_t)b * Hh + h) * Kk + k];
    }
    #pragma unroll
    for (int ii = 0; ii < 16; ii++) {     // ks stage (float4 in) + Kc copy
        int f = ii * 128 + t;
        int kq = f & 31, mm = f >> 5;
        size_t src = ((size_t)b * Mm + (m0 + mm)) * Kk + kq * 4;
        float4 v = *(const float4*)&prevK[src];
        *(float4*)&outKc[((size_t)b * MC + (m0 + mm)) * Kk + kq * 4] = v;
        float* dst = &ks[mm * 129 + kq * 4];
        dst[0] = v.x; dst[1] = v.y; dst[2] = v.z; dst[3] = v.w;
    }
    __syncthreads();
    const int mg = t & 15, hg = t >> 4;       // 16 x 8
    const int mt = mg * 4, h0 = hg * 4;
    float acc[4][4] = {};                     // [h][m]
    for (int k = 0; k < 128; k++) {
        float4 q4 = *(float4*)&qs[k * 36 + h0];
        float qa[4] = {q4.x, q4.y, q4.z, q4.w};
        float kk[4];
        #pragma unroll
        for (int c = 0; c < 4; c++) kk[c] = ks[(mt + c) * 129 + k];
        #pragma unroll
        for (int a = 0; a < 4; a++)
            #pragma unroll
            for (int c = 0; c < 4; c++)
                acc[a][c] = fmaf(qa[a], kk[c], acc[a][c]);
    }
    #pragma unroll
    for (int a = 0; a < 4; a++)
        #pragma unroll
        for (int c = 0; c < 4; c++)
            logits[((size_t)(b * Hh + h0 + a)) * MC + m0 + mt + c] = acc[a][c];
}

// ---------------- K2b: Kc[:,M,:] = new_k ; logits[:, :, M] = q . new_k
__global__ __launch_bounds__(256) void k2b_newrow_logits(const float* __restrict__ ws,
        float* __restrict__ outKc) {
    const int b = blockIdx.x, t = threadIdx.x;
    const float* newk = ws + WS_NEWK;
    const float* q    = ws + WS_Q;
    float* logits = (float*)(ws + WS_LOGITS);
    if (t < 128) outKc[((size_t)b * MC + Mm) * Kk + t] = newk[b * Kk + t];
    int h = t >> 3, j = t & 7;
    float s = 0.f;
    #pragma unroll
    for (int c = 0; c < 16; c++) {
        int k = j + c * 8;
        s += q[((size_t)b * Hh + h) * Kk + k] * newk[b * Kk + k];
    }
    s += __shfl_xor(s, 1, 64);
    s += __shfl_xor(s, 2, 64);
    s += __shfl_xor(s, 4, 64);
    if (j == 0) logits[((size_t)(b * Hh + h)) * MC + Mm] = s;
}

// ---------------- K3: per (b,h) row: max and sum(exp(l - max))
__global__ __launch_bounds__(256) void k3_stats(const float* __restrict__ logits,
        float* __restrict__ smax, float* __restrict__ ssum) {
    const int bh = blockIdx.x, t = threadIdx.x;
    const float* row = logits + (size_t)bh * MC;
    float v[17];
    #pragma unroll
    for (int i = 0; i < 17; i++) {
        int idx = i * 256 + t;
        v[i] = (idx < MC) ? row[idx] : -3.0e38f;
    }
    float m = v[0];
    #pragma unroll
    for (int i = 1; i < 17; i++) m = fmaxf(m, v[i]);
    #pragma unroll
    for (int off = 32; off; off >>= 1) m = fmaxf(m, __shfl_xor(m, off, 64));
    __shared__ float red[4];
    if ((t & 63) == 0) red[t >> 6] = m;
    __syncthreads();
    m = fmaxf(fmaxf(red[0], red[1]), fmaxf(red[2], red[3]));
    float s = 0.f;
    #pragma unroll
    for (int i = 0; i < 17; i++) s += __expf(v[i] - m);
    #pragma unroll
    for (int off = 32; off; off >>= 1) s += __shfl_xor(s, off, 64);
    __syncthreads();
    if ((t & 63) == 0) red[t >> 6] = s;
    __syncthreads();
    if (t == 0) {
        smax[bh] = m;
        ssum[bh] = red[0] + red[1] + red[2] + red[3];
    }
}

// ---------------- K4: copy prev_V -> Vc, fused partial O += w * Vc
// grid (16 m-supertiles of 256, 64 b), block 128
__global__ __launch_bounds__(128) void k4_vcopy_pv(const float* __restrict__ prevV,
        const float* __restrict__ logits, const float* __restrict__ smax,
        const float* __restrict__ ssum, float* __restrict__ outVc,
        float* __restrict__ O) {
    const int mbase = blockIdx.x * 256;
    const int b = blockIdx.y;
    const int t = threadIdx.x;
    __shared__ float vs[64 * 132];   // [m][v], natural, 16B-aligned rows
    __shared__ float wl[32 * 65];    // [h][m], natural (no transpose)
    __shared__ float mxs[32], rss[32];
    if (t < 32) { mxs[t] = smax[b * Hh + t]; rss[t] = 1.f / ssum[b * Hh + t]; }
    __syncthreads();
    const int vg = t & 15, hg = t >> 4;       // 16 x 8
    const int v0 = vg * 8, h0 = hg * 4;
    float acc[4][8] = {};   // [h][v]
    for (int st = 0; st < 4; st++) {
        const int m0 = mbase + st * 64;
        #pragma unroll
        for (int ii = 0; ii < 16; ii++) {   // V stage (float4) + Vc copy
            int f = ii * 128 + t;
            int vq = f & 31, mm = f >> 5;
            float4 vv = *(const float4*)&prevV[((size_t)b * Mm + m0 + mm) * Vv + vq * 4];
            *(float4*)&outVc[((size_t)b * MC + m0 + mm) * Vv + vq * 4] = vv;
            *(float4*)&vs[mm * 132 + vq * 4] = vv;
        }
        #pragma unroll
        for (int ii = 0; ii < 16; ii++) {   // weights stage, m-fast (coalesced)
            int f = ii * 128 + t;
            int mm = f & 63, h = f >> 6;
            float l = logits[((size_t)(b * Hh + h)) * MC + m0 + mm];
            wl[h * 65 + mm] = __expf(l - mxs[h]) * rss[h];
        }
        __syncthreads();
        for (int mm = 0; mm < 64; mm++) {
            float w[4];
            #pragma unroll
            for (int a = 0; a < 4; a++) w[a] = wl[(h0 + a) * 65 + mm];
            float4 va = *(float4*)&vs[mm * 132 + v0];
            float4 vb = *(float4*)&vs[mm * 132 + v0 + 4];
            float vv[8] = {va.x, va.y, va.z, va.w, vb.x, vb.y, vb.z, vb.w};
            #pragma unroll
            for (int a = 0; a < 4; a++)
                #pragma unroll
                for (int c = 0; c < 8; c++)
                    acc[a][c] = fmaf(w[a], vv[c], acc[a][c]);
        }
        __syncthreads();
    }
    #pragma unroll
    for (int a = 0; a < 4; a++)
        #pragma unroll
        for (int c = 0; c < 8; c++)
            atomicAdd(&O[((size_t)(b * Hh + h0 + a)) * Vv + v0 + c], acc[a][c]);
}

// ---------------- K4b: Vc[:,M,:] = new_v ; O += w[:, :, M] * new_v
__global__ __launch_bounds__(256) void k4b_newrow_pv(const float* __restrict__ ws,
        float* __restrict__ outVc, float* __restrict__ O) {
    const int b = blockIdx.x, t = threadIdx.x;
    const float* newv   = ws + WS_NEWV;
    const float* logits = ws + WS_LOGITS;
    const float* smax   = ws + WS_SMAX;
    const float* ssum   = ws + WS_SSUM;
    __shared__ float wm[32];
    if (t < 32) {
        float l = logits[((size_t)(b * Hh + t)) * MC + Mm];
        wm[t] = __expf(l - smax[b * Hh + t]) / ssum[b * Hh + t];
    }
    __syncthreads();
    int v = t & 127, hg = t >> 7;
    float nv = newv[b * Vv + v];
    if (t < 128) outVc[((size_t)b * MC + Mm) * Vv + v] = nv;
    #pragma unroll
    for (int hh = 0; hh < 16; hh++) {
        int h = hg * 16 + hh;
        atomicAdd(&O[((size_t)(b * Hh + h)) * Vv + v], wm[h] * nv);
    }
}

// ---------------- K5: y[b,d] = sum_{h,v} O[b,h,v] * P_o[h,d,v]
// grid (64 d-tiles of 64, 8 h-quads of 4). Dot along v, both tiles natural.
__global__ __launch_bounds__(256) void k5_outproj(const float* __restrict__ O,
        const float* __restrict__ Po, float* __restrict__ y) {
    const int dbase = blockIdx.x * 64;
    const int hq = blockIdx.y;               // 4 h each
    const int t = threadIdx.x;
    __shared__ float os[64 * 68];  // [b][v-half]
    __shared__ float ps2[64 * 68]; // [d][v-half]
    const int dg = t & 15, bg = t >> 4;
    const int d0 = dg * 4, b0 = bg * 4;
    float acc[4][4] = {};   // [b][d]
    for (int hi = 0; hi < 4; hi++) {
        const int h = hq * 4 + hi;
        for (int vh = 0; vh < 2; vh++) {
            #pragma unroll
            for (int ii = 0; ii < 4; ii++) {
                int f = ii * 256 + t;
                int vq = f & 15, r = f >> 4;
                *(float4*)&os[r * 68 + vq * 4] =
                    *(const float4*)&O[((size_t)(r * Hh + h)) * Vv + vh * 64 + vq * 4];
                *(float4*)&ps2[r * 68 + vq * 4] =
                    *(const float4*)&Po[((size_t)h * Dd + dbase + r) * Vv + vh * 64 + vq * 4];
            }
            __syncthreads();
            #pragma unroll
            for (int v4 = 0; v4 < 16; v4++) {
                float4 pd[4], ob[4];
                #pragma unroll
                for (int c = 0; c < 4; c++) pd[c] = *(float4*)&ps2[(d0 + c) * 68 + v4 * 4];
                #pragma unroll
                for (int a = 0; a < 4; a++) ob[a] = *(float4*)&os[(b0 + a) * 68 + v4 * 4];
                #pragma unroll
                for (int a = 0; a < 4; a++)
                    #pragma unroll
                    for (int c = 0; c < 4; c++) {
                        acc[a][c] = fmaf(ob[a].x, pd[c].x, acc[a][c]);
                        acc[a][c] = fmaf(ob[a].y, pd[c].y, acc[a][c]);
                        acc[a][c] = fmaf(ob[a].z, pd[c].z, acc[a][c]);
                        acc[a][c] = fmaf(ob[a].w, pd[c].w, acc[a][c]);
                    }
            }
            __syncthreads();
        }
    }
    #pragma unroll
    for (int a = 0; a < 4; a++)
        #pragma unroll
        for (int c = 0; c < 4; c++)
            atomicAdd(&y[(size_t)(b0 + a) * Dd + dbase + d0 + c], acc[a][c]);
}

extern "C" void kernel_launch(void* const* d_in, const int* in_sizes, int n_in,
                              void* d_out, int out_size, void* d_ws, size_t ws_size,
                              hipStream_t stream) {
    const float* x     = (const float*)d_in[0];
    const float* prevK = (const float*)d_in[1];
    const float* prevV = (const float*)d_in[2];
    const float* Pq    = (const float*)d_in[3];
    const float* Pk    = (const float*)d_in[4];
    const float* Pv    = (const float*)d_in[5];
    const float* Po    = (const float*)d_in[6];
    float* out = (float*)d_out;
    float* ws  = (float*)d_ws;

    // zero the atomically-accumulated buffers (q/new_k/new_v, O, y)
    hipMemsetAsync(ws + WS_Q, 0, (size_t)(WS_LOGITS - WS_Q) * sizeof(float), stream);
    hipMemsetAsync(ws + WS_O, 0, (size_t)(Bb * Hh * Vv) * sizeof(float), stream);
    hipMemsetAsync(out + OUT_Y, 0, (size_t)(Bb * Dd) * sizeof(float), stream);

    k1_proj<<<dim3(Hh + 2, 32), 256, 0, stream>>>(x, Pq, Pk, Pv, ws);
    k2_kcopy_logits<<<dim3(64, Bb), 128, 0, stream>>>(prevK, ws + WS_Q,
                                                      out + OUT_KC, ws + WS_LOGITS);
    k2b_newrow_logits<<<Bb, 256, 0, stream>>>(ws, out + OUT_KC);
    k3_stats<<<Bb * Hh, 256, 0, stream>>>(ws + WS_LOGITS, ws + WS_SMAX, ws + WS_SSUM);
    k4_vcopy_pv<<<dim3(16, Bb), 128, 0, stream>>>(prevV, ws + WS_LOGITS, ws + WS_SMAX,
                                                  ws + WS_SSUM, out + OUT_VC, ws + WS_O);
    k4b_newrow_pv<<<Bb, 256, 0, stream>>>(ws, out + OUT_VC, ws + WS_O);
    k5_outproj<<<dim3(64, 8), 256, 0, stream>>>(ws + WS_O, Po, out + OUT_Y);
}

// Round 3
// 326.649 us; speedup vs baseline: 1.9363x; 1.9363x over previous
//
#include <hip/hip_runtime.h>
#include <math.h>

#define Bb 64
#define Dd 4096
#define Hh 32
#define Kk 128
#define Vv 128
#define Mm 4096
#define MC 4097

// workspace layout (float offsets)
// WS_PART is a union region reused three times (stream-ordered):
//   1) k1 partials: 34 proj x 16 chunks x 8192      = 4456448 floats
//   2) k4 O-partials: 9 slots x 262144              = 2359296 floats
//   3) k5 y-partials: 8 slots x 262144              = 2097152 floats
#define WS_PART   0
#define WS_Q      4456448
#define WS_NEWK   (WS_Q + Bb*Hh*Kk)        // +262144
#define WS_NEWV   (WS_NEWK + Bb*Kk)        // +8192
#define WS_LOGITS (WS_NEWV + Bb*Vv)        // +8192
#define WS_SMAX   (WS_LOGITS + Bb*Hh*MC)   // +8390656
#define WS_SSUM   (WS_SMAX + Bb*Hh)
#define WS_O      (WS_SSUM + Bb*Hh)

#define OSLOT (Bb*Hh*Vv)                   // 262144
#define YSLOT (Bb*Dd)                      // 262144

// d_out layout (float offsets): y, Kc, Vc
#define OUT_Y  0
#define OUT_KC (Bb*Dd)
#define OUT_VC (OUT_KC + Bb*MC*Kk)

// ---------------- K1A: partial projections over d-chunk of 256
// grid (34, 16): x = proj index (0..31 heads, 32=P_k, 33=P_v), y = d-chunk
__global__ __launch_bounds__(256) void k1A_proj(const float* __restrict__ x,
        const float* __restrict__ Pq, const float* __restrict__ Pk,
        const float* __restrict__ Pv, float* __restrict__ part) {
    const int hidx = blockIdx.x;
    const int d0c  = blockIdx.y * 256;
    const int t = threadIdx.x;
    const int kg = t & 15, bg = t >> 4;
    const int k0 = kg * 8, b0 = bg * 4;

    const float* P;
    if (hidx < Hh)       P = Pq + (size_t)hidx * Dd * Kk;
    else if (hidx == Hh) P = Pk;
    else                 P = Pv;

    __shared__ float xs[32 * 65];      // [d-sub][b], stride 65 -> conflict-free
    __shared__ float ps[32 * 128];     // [d-sub][k], natural

    float acc[4][8];
    #pragma unroll
    for (int a = 0; a < 4; a++)
        #pragma unroll
        for (int c = 0; c < 8; c++) acc[a][c] = 0.f;

    for (int tt = 0; tt < 8; tt++) {
        const int d0 = d0c + tt * 32;
        #pragma unroll
        for (int ii = 0; ii < 8; ii++) {
            int f = ii * 256 + t;
            int i = f & 31, bb = f >> 5;
            xs[i * 65 + bb] = x[(size_t)bb * Dd + d0 + i];
        }
        #pragma unroll
        for (int ii = 0; ii < 4; ii++) {
            int f = ii * 256 + t;
            int i = f >> 5, k4 = (f & 31) * 4;
            *(float4*)&ps[i * 128 + k4] = *(const float4*)&P[(size_t)(d0 + i) * Kk + k4];
        }
        __syncthreads();
        #pragma unroll
        for (int i = 0; i < 32; i++) {
            float xb[4];
            #pragma unroll
            for (int a = 0; a < 4; a++) xb[a] = xs[i * 65 + b0 + a];
            float4 p0 = *(float4*)&ps[i * 128 + k0];
            float4 p1 = *(float4*)&ps[i * 128 + k0 + 4];
            float pp[8] = {p0.x, p0.y, p0.z, p0.w, p1.x, p1.y, p1.z, p1.w};
            #pragma unroll
            for (int a = 0; a < 4; a++)
                #pragma unroll
                for (int c = 0; c < 8; c++)
                    acc[a][c] = fmaf(xb[a], pp[c], acc[a][c]);
        }
        __syncthreads();
    }
    float* dst = part + ((size_t)hidx * 16 + blockIdx.y) * 8192;
    #pragma unroll
    for (int a = 0; a < 4; a++) {
        int b = b0 + a;
        *(float4*)&dst[b * 128 + k0]     = make_float4(acc[a][0], acc[a][1], acc[a][2], acc[a][3]);
        *(float4*)&dst[b * 128 + k0 + 4] = make_float4(acc[a][4], acc[a][5], acc[a][6], acc[a][7]);
    }
}

// ---------------- K1B: reduce 16 chunks -> q / new_k / new_v
__global__ __launch_bounds__(256) void k1B_reduce(const float* __restrict__ part,
        float* __restrict__ ws) {
    const int o = blockIdx.x * 256 + threadIdx.x;   // 34*8192 total
    const int hidx = o >> 13;
    const int rest = o & 8191;
    float s = 0.f;
    #pragma unroll
    for (int c = 0; c < 16; c++) s += part[((size_t)hidx * 16 + c) * 8192 + rest];
    if (hidx < Hh) {
        int b = rest >> 7, k = rest & 127;
        ws[WS_Q + ((size_t)b * Hh + hidx) * Kk + k] = s;
    } else if (hidx == Hh) {
        ws[WS_NEWK + rest] = s;
    } else {
        ws[WS_NEWV + rest] = s;
    }
}

// ---------------- K2: copy prev_K -> Kc, fused logits[b,h,m] = q[b,h,:].Kc[b,m,:]
// grid (64 m-tiles, 64 b), block 128. K kept NATURAL [m][k] (stride 129).
__global__ __launch_bounds__(128) void k2_kcopy_logits(const float* __restrict__ prevK,
        const float* __restrict__ wq, float* __restrict__ outKc,
        float* __restrict__ logits) {
    const int m0 = blockIdx.x * 64;
    const int b  = blockIdx.y;
    const int t  = threadIdx.x;
    __shared__ float qs[128 * 36];   // [k][h], padded
    __shared__ float ks[64 * 129];   // [m][k], stride 129 -> conflict-free

    #pragma unroll
    for (int ii = 0; ii < 32; ii++) {     // qs transpose-stage, h-fast (free writes)
        int f = ii * 128 + t;
        int h = f & 31, k = f >> 5;
        qs[k * 36 + h] = wq[((size_t)b * Hh + h) * Kk + k];
    }
    #pragma unroll
    for (int ii = 0; ii < 16; ii++) {     // ks stage (float4 in) + Kc copy
        int f = ii * 128 + t;
        int kq = f & 31, mm = f >> 5;
        size_t src = ((size_t)b * Mm + (m0 + mm)) * Kk + kq * 4;
        float4 v = *(const float4*)&prevK[src];
        *(float4*)&outKc[((size_t)b * MC + (m0 + mm)) * Kk + kq * 4] = v;
        float* dst = &ks[mm * 129 + kq * 4];
        dst[0] = v.x; dst[1] = v.y; dst[2] = v.z; dst[3] = v.w;
    }
    __syncthreads();
    const int mg = t & 15, hg = t >> 4;       // 16 x 8
    const int mt = mg * 4, h0 = hg * 4;
    float acc[4][4] = {};                     // [h][m]
    for (int k = 0; k < 128; k++) {
        float4 q4 = *(float4*)&qs[k * 36 + h0];
        float qa[4] = {q4.x, q4.y, q4.z, q4.w};
        float kk[4];
        #pragma unroll
        for (int c = 0; c < 4; c++) kk[c] = ks[(mt + c) * 129 + k];
        #pragma unroll
        for (int a = 0; a < 4; a++)
            #pragma unroll
            for (int c = 0; c < 4; c++)
                acc[a][c] = fmaf(qa[a], kk[c], acc[a][c]);
    }
    #pragma unroll
    for (int a = 0; a < 4; a++)
        *(float4*)&logits[((size_t)(b * Hh + h0 + a)) * MC + m0 + mt] =
            make_float4(acc[a][0], acc[a][1], acc[a][2], acc[a][3]);
}

// ---------------- K2b: Kc[:,M,:] = new_k ; logits[:, :, M] = q . new_k
__global__ __launch_bounds__(256) void k2b_newrow_logits(const float* __restrict__ ws,
        float* __restrict__ outKc) {
    const int b = blockIdx.x, t = threadIdx.x;
    const float* newk = ws + WS_NEWK;
    const float* q    = ws + WS_Q;
    float* logits = (float*)(ws + WS_LOGITS);
    if (t < 128) outKc[((size_t)b * MC + Mm) * Kk + t] = newk[b * Kk + t];
    int h = t >> 3, j = t & 7;
    float s = 0.f;
    #pragma unroll
    for (int c = 0; c < 16; c++) {
        int k = j + c * 8;
        s += q[((size_t)b * Hh + h) * Kk + k] * newk[b * Kk + k];
    }
    s += __shfl_xor(s, 1, 64);
    s += __shfl_xor(s, 2, 64);
    s += __shfl_xor(s, 4, 64);
    if (j == 0) logits[((size_t)(b * Hh + h)) * MC + Mm] = s;
}

// ---------------- K3: per (b,h) row: max and sum(exp(l - max))
__global__ __launch_bounds__(256) void k3_stats(const float* __restrict__ logits,
        float* __restrict__ smax, float* __restrict__ ssum) {
    const int bh = blockIdx.x, t = threadIdx.x;
    const float* row = logits + (size_t)bh * MC;
    float v[17];
    #pragma unroll
    for (int i = 0; i < 17; i++) {
        int idx = i * 256 + t;
        v[i] = (idx < MC) ? row[idx] : -3.0e38f;
    }
    float m = v[0];
    #pragma unroll
    for (int i = 1; i < 17; i++) m = fmaxf(m, v[i]);
    #pragma unroll
    for (int off = 32; off; off >>= 1) m = fmaxf(m, __shfl_xor(m, off, 64));
    __shared__ float red[4];
    if ((t & 63) == 0) red[t >> 6] = m;
    __syncthreads();
    m = fmaxf(fmaxf(red[0], red[1]), fmaxf(red[2], red[3]));
    float s = 0.f;
    #pragma unroll
    for (int i = 0; i < 17; i++) s += __expf(v[i] - m);
    #pragma unroll
    for (int off = 32; off; off >>= 1) s += __shfl_xor(s, off, 64);
    __syncthreads();
    if ((t & 63) == 0) red[t >> 6] = s;
    __syncthreads();
    if (t == 0) {
        smax[bh] = m;
        ssum[bh] = red[0] + red[1] + red[2] + red[3];
    }
}

// ---------------- K4: copy prev_V -> Vc, fused partial O_part[slot] = w * Vc
// grid (8 m-supertiles of 512, 64 b), block 128. Plain stores, no atomics.
__global__ __launch_bounds__(128) void k4_vcopy_pv(const float* __restrict__ prevV,
        const float* __restrict__ logits, const float* __restrict__ smax,
        const float* __restrict__ ssum, float* __restrict__ outVc,
        float* __restrict__ Opart) {
    const int mbase = blockIdx.x * 512;
    const int b = blockIdx.y;
    const int t = threadIdx.x;
    __shared__ float vs[64 * 132];   // [m][v], natural, 16B-aligned rows
    __shared__ float wl[32 * 65];    // [h][m], natural
    __shared__ float mxs[32], rss[32];
    if (t < 32) { mxs[t] = smax[b * Hh + t]; rss[t] = 1.f / ssum[b * Hh + t]; }
    __syncthreads();
    const int vg = t & 15, hg = t >> 4;       // 16 x 8
    const int v0 = vg * 8, h0 = hg * 4;
    float acc[4][8] = {};   // [h][v]
    for (int st = 0; st < 8; st++) {
        const int m0 = mbase + st * 64;
        #pragma unroll
        for (int ii = 0; ii < 16; ii++) {   // V stage (float4) + Vc copy
            int f = ii * 128 + t;
            int vq = f & 31, mm = f >> 5;
            float4 vv = *(const float4*)&prevV[((size_t)b * Mm + m0 + mm) * Vv + vq * 4];
            *(float4*)&outVc[((size_t)b * MC + m0 + mm) * Vv + vq * 4] = vv;
            *(float4*)&vs[mm * 132 + vq * 4] = vv;
        }
        #pragma unroll
        for (int ii = 0; ii < 16; ii++) {   // weights stage, m-fast (coalesced)
            int f = ii * 128 + t;
            int mm = f & 63, h = f >> 6;
            float l = logits[((size_t)(b * Hh + h)) * MC + m0 + mm];
            wl[h * 65 + mm] = __expf(l - mxs[h]) * rss[h];
        }
        __syncthreads();
        for (int mm = 0; mm < 64; mm++) {
            float w[4];
            #pragma unroll
            for (int a = 0; a < 4; a++) w[a] = wl[(h0 + a) * 65 + mm];
            float4 va = *(float4*)&vs[mm * 132 + v0];
            float4 vb = *(float4*)&vs[mm * 132 + v0 + 4];
            float vv[8] = {va.x, va.y, va.z, va.w, vb.x, vb.y, vb.z, vb.w};
            #pragma unroll
            for (int a = 0; a < 4; a++)
                #pragma unroll
                for (int c = 0; c < 8; c++)
                    acc[a][c] = fmaf(w[a], vv[c], acc[a][c]);
        }
        __syncthreads();
    }
    float* op = Opart + (size_t)blockIdx.x * OSLOT;
    #pragma unroll
    for (int a = 0; a < 4; a++) {
        size_t idx = ((size_t)b * Hh + h0 + a) * Vv + v0;
        *(float4*)&op[idx]     = make_float4(acc[a][0], acc[a][1], acc[a][2], acc[a][3]);
        *(float4*)&op[idx + 4] = make_float4(acc[a][4], acc[a][5], acc[a][6], acc[a][7]);
    }
}

// ---------------- K4b: Vc[:,M,:] = new_v ; O_part[8] = w[:, :, M] * new_v
__global__ __launch_bounds__(256) void k4b_newrow_pv(const float* __restrict__ ws,
        float* __restrict__ outVc, float* __restrict__ Opart) {
    const int b = blockIdx.x, t = threadIdx.x;
    const float* newv   = ws + WS_NEWV;
    const float* logits = ws + WS_LOGITS;
    const float* smax   = ws + WS_SMAX;
    const float* ssum   = ws + WS_SSUM;
    __shared__ float wm[32];
    if (t < 32) {
        float l = logits[((size_t)(b * Hh + t)) * MC + Mm];
        wm[t] = __expf(l - smax[b * Hh + t]) / ssum[b * Hh + t];
    }
    __syncthreads();
    int v = t & 127, hg = t >> 7;
    float nv = newv[b * Vv + v];
    if (t < 128) outVc[((size_t)b * MC + Mm) * Vv + v] = nv;
    float* op = Opart + (size_t)8 * OSLOT;
    #pragma unroll
    for (int hh = 0; hh < 16; hh++) {
        int h = hg * 16 + hh;
        op[((size_t)b * Hh + h) * Vv + v] = wm[h] * nv;
    }
}

// ---------------- K4c: O = sum of 9 partial slots
__global__ __launch_bounds__(256) void k4c_oreduce(const float* __restrict__ Opart,
        float* __restrict__ O) {
    const int o = blockIdx.x * 256 + threadIdx.x;
    float s = 0.f;
    #pragma unroll
    for (int c = 0; c < 9; c++) s += Opart[(size_t)c * OSLOT + o];
    O[o] = s;
}

// ---------------- K5: y_part[hq][b,d] = sum_{h in quad, v} O[b,h,v] * P_o[h,d,v]
// grid (64 d-tiles of 64, 8 h-quads of 4)
__global__ __launch_bounds__(256) void k5_outproj(const float* __restrict__ O,
        const float* __restrict__ Po, float* __restrict__ ypart) {
    const int dbase = blockIdx.x * 64;
    const int hq = blockIdx.y;
    const int t = threadIdx.x;
    __shared__ float os[64 * 68];  // [b][v-half]
    __shared__ float ps2[64 * 68]; // [d][v-half]
    const int dg = t & 15, bg = t >> 4;
    const int d0 = dg * 4, b0 = bg * 4;
    float acc[4][4] = {};   // [b][d]
    for (int hi = 0; hi < 4; hi++) {
        const int h = hq * 4 + hi;
        for (int vh = 0; vh < 2; vh++) {
            #pragma unroll
            for (int ii = 0; ii < 4; ii++) {
                int f = ii * 256 + t;
                int vq = f & 15, r = f >> 4;
                *(float4*)&os[r * 68 + vq * 4] =
                    *(const float4*)&O[((size_t)(r * Hh + h)) * Vv + vh * 64 + vq * 4];
                *(float4*)&ps2[r * 68 + vq * 4] =
                    *(const float4*)&Po[((size_t)h * Dd + dbase + r) * Vv + vh * 64 + vq * 4];
            }
            __syncthreads();
            #pragma unroll
            for (int v4 = 0; v4 < 16; v4++) {
                float4 pd[4], ob[4];
                #pragma unroll
                for (int c = 0; c < 4; c++) pd[c] = *(float4*)&ps2[(d0 + c) * 68 + v4 * 4];
                #pragma unroll
                for (int a = 0; a < 4; a++) ob[a] = *(float4*)&os[(b0 + a) * 68 + v4 * 4];
                #pragma unroll
                for (int a = 0; a < 4; a++)
                    #pragma unroll
                    for (int c = 0; c < 4; c++) {
                        acc[a][c] = fmaf(ob[a].x, pd[c].x, acc[a][c]);
                        acc[a][c] = fmaf(ob[a].y, pd[c].y, acc[a][c]);
                        acc[a][c] = fmaf(ob[a].z, pd[c].z, acc[a][c]);
                        acc[a][c] = fmaf(ob[a].w, pd[c].w, acc[a][c]);
                    }
            }
            __syncthreads();
        }
    }
    float* yp = ypart + (size_t)hq * YSLOT;
    #pragma unroll
    for (int a = 0; a < 4; a++)
        *(float4*)&yp[(size_t)(b0 + a) * Dd + dbase + d0] =
            make_float4(acc[a][0], acc[a][1], acc[a][2], acc[a][3]);
}

// ---------------- K5r: y = sum of 8 y-partial slots
__global__ __launch_bounds__(256) void k5r_yreduce(const float* __restrict__ ypart,
        float* __restrict__ y) {
    const int o = blockIdx.x * 256 + threadIdx.x;
    float s = 0.f;
    #pragma unroll
    for (int c = 0; c < 8; c++) s += ypart[(size_t)c * YSLOT + o];
    y[o] = s;
}

extern "C" void kernel_launch(void* const* d_in, const int* in_sizes, int n_in,
                              void* d_out, int out_size, void* d_ws, size_t ws_size,
                              hipStream_t stream) {
    const float* x     = (const float*)d_in[0];
    const float* prevK = (const float*)d_in[1];
    const float* prevV = (const float*)d_in[2];
    const float* Pq    = (const float*)d_in[3];
    const float* Pk    = (const float*)d_in[4];
    const float* Pv    = (const float*)d_in[5];
    const float* Po    = (const float*)d_in[6];
    float* out = (float*)d_out;
    float* ws  = (float*)d_ws;

    k1A_proj<<<dim3(Hh + 2, 16), 256, 0, stream>>>(x, Pq, Pk, Pv, ws + WS_PART);
    k1B_reduce<<<(34 * 8192) / 256, 256, 0, stream>>>(ws + WS_PART, ws);
    k2_kcopy_logits<<<dim3(64, Bb), 128, 0, stream>>>(prevK, ws + WS_Q,
                                                      out + OUT_KC, ws + WS_LOGITS);
    k2b_newrow_logits<<<Bb, 256, 0, stream>>>(ws, out + OUT_KC);
    k3_stats<<<Bb * Hh, 256, 0, stream>>>(ws + WS_LOGITS, ws + WS_SMAX, ws + WS_SSUM);
    k4_vcopy_pv<<<dim3(8, Bb), 128, 0, stream>>>(prevV, ws + WS_LOGITS, ws + WS_SMAX,
                                                 ws + WS_SSUM, out + OUT_VC, ws + WS_PART);
    k4b_newrow_pv<<<Bb, 256, 0, stream>>>(ws, out + OUT_VC, ws + WS_PART);
    k4c_oreduce<<<OSLOT / 256, 256, 0, stream>>>(ws + WS_PART, ws + WS_O);
    k5_outproj<<<dim3(64, 8), 256, 0, stream>>>(ws + WS_O, Po, ws + WS_PART);
    k5r_yreduce<<<YSLOT / 256, 256, 0, stream>>>(ws + WS_PART, out + OUT_Y);
}